// Round 2
// baseline (351.971 us; speedup 1.0000x reference)
//
#include <hip/hip_runtime.h>

// ---------------------------------------------------------------------------
// QTranBase: twin 3-layer MLPs via bf16 MFMA.
// R2: convert_x eliminated (fp32->bf16 fused into layer-1 staging via
// v_perm trunc-pack + padded LDS rows); Q+V merged per layer; occupancy
// bound removed (m97 ran 3 blocks/CU at 164 VGPR).
// ---------------------------------------------------------------------------

#define ROWS 32768
#define EMBED 512

using frag_ab = __attribute__((ext_vector_type(8))) short;   // 8 x bf16
using f32x4   = __attribute__((ext_vector_type(4))) float;   // MFMA C/D

__device__ __forceinline__ unsigned short f2bf(float f) {
    // round-to-nearest-even (used for weights + h1 writeback)
    unsigned int u = __builtin_bit_cast(unsigned int, f);
    return (unsigned short)((u + 0x7fffu + ((u >> 16) & 1u)) >> 16);
}

// pack two fp32 -> bf16x2 by truncation: lo -> low 16, hi -> high 16.
// v_perm_b32 d, s0, s1, sel : byte idx 0-3 = s1 bytes, 4-7 = s0 bytes.
__device__ __forceinline__ unsigned pk2(float lo, float hi) {
    return __builtin_amdgcn_perm(__builtin_bit_cast(unsigned, hi),
                                 __builtin_bit_cast(unsigned, lo), 0x07060302u);
}

__device__ __forceinline__ void async_copy16(const void* g, void* l) {
    __builtin_amdgcn_global_load_lds(
        (const __attribute__((address_space(1))) unsigned int*)g,
        (__attribute__((address_space(3))) unsigned int*)l, 16, 0, 0);
}

// --- out[i] = (i < ROWS) ? Qb3 : Vb3  (layer-3 bias pre-seeded for atomics)
__global__ void init_out(float* __restrict__ out,
                         const float* __restrict__ qb3,
                         const float* __restrict__ vb3) {
    int i = blockIdx.x * 256 + threadIdx.x;
    out[i] = (i < ROWS) ? qb3[0] : vb3[0];
}

// --- Wt[n][k] = bf16(W[k][n]) for the four big weight matrices
__global__ void prep_w(const float* __restrict__ Qw1, const float* __restrict__ Qw2,
                       const float* __restrict__ Vw1, const float* __restrict__ Vw2,
                       unsigned short* __restrict__ Qw1t, unsigned short* __restrict__ Qw2t,
                       unsigned short* __restrict__ Vw1t, unsigned short* __restrict__ Vw2t) {
    int t = blockIdx.x * 256 + threadIdx.x;
    if (t < 512 * 1024) {                      // Qw1: [1024][512] -> [512][1024]
        int n = t >> 10, k = t & 1023;
        Qw1t[t] = f2bf(Qw1[(size_t)k * 512 + n]);
    } else {
        t -= 512 * 1024;
        int seg = t >> 18;                     // 262144-element segments
        int r = t & 0x3ffff;
        int n = r >> 9, k = r & 511;
        const float* W = (seg == 0) ? Qw2 : (seg == 1) ? Vw1 : Vw2;
        unsigned short* O = (seg == 0) ? Qw2t : (seg == 1) ? Vw1t : Vw2t;
        O[r] = f2bf(W[(size_t)k * 512 + n]);
    }
}

// ---------------------------------------------------------------------------
// Layer 1 (Q and V in one launch): h1 = relu(A @ Wt^T + bias), A is fp32.
// blockIdx.x < 4 -> Q (A = [states|actions], K=1024), >= 4 -> V (states, K=512).
// A: fp32 float4 register prefetch -> v_perm trunc-pack -> ds_write into
// 80 B-padded rows (frag-read bank groups 5r mod 8 -> 2-way = free).
// B: bf16 weights via async global_load_lds (m97 path).
// ---------------------------------------------------------------------------
__global__ __launch_bounds__(256)
void layer1(const float* __restrict__ states, const float* __restrict__ actions,
            const unsigned short* __restrict__ Qw1t,
            const unsigned short* __restrict__ Vw1t,
            const float* __restrict__ Qb1, const float* __restrict__ Vb1,
            unsigned short* __restrict__ h1Q, unsigned short* __restrict__ h1V) {
    __shared__ __align__(16) unsigned short As[128 * 40];   // 10 KB, 80 B rows
    __shared__ __align__(16) unsigned short Bs[128 * 32];   // 8 KB

    const int tid = threadIdx.x, wave = tid >> 6, lane = tid & 63;
    const bool isV = blockIdx.x >= 4;
    const int bn = (blockIdx.x & 3) * 128;
    const int bm = blockIdx.y * 128;
    const int K   = isV ? 512 : 1024;
    const int ldb = isV ? 512 : 1024;
    const unsigned short* Wt = isV ? Vw1t : Qw1t;
    const float* bias = isV ? Vb1 : Qb1;
    unsigned short* H = isV ? h1V : h1Q;

    const int wm = (wave & 1) * 64, wn = (wave >> 1) * 64;
    const int lrow = lane & 15, quad = lane >> 4;
    f32x4 acc[4][4] = {};

    // B staging: per-wave 1 KB chunks, 64 B rows
    const int lin  = wave * 1024 + lane * 16;
    const int rowS = lin >> 6, colS = (lin & 63) >> 1;
    const unsigned short* gB0 = Wt + (size_t)(bn + rowS)      * ldb + colS;
    const unsigned short* gB1 = Wt + (size_t)(bn + rowS + 64) * ldb + colS;
    unsigned short* ldsB0 = Bs + wave * 512;
    unsigned short* ldsB1 = Bs + 2048 + wave * 512;

    // A staging: thread t handles row t>>1, k-half t&1 (16 fp32 = 64 B)
    const int arow = tid >> 1, ahalf = tid & 1;
    const size_t rowOff = (size_t)(bm + arow) * 512 + ahalf * 16;
    unsigned short* wp = As + arow * 40 + ahalf * 16;

    float4 f0, f1, f2, f3;
    { const float4* g = (const float4*)(states + rowOff);
      f0 = g[0]; f1 = g[1]; f2 = g[2]; f3 = g[3]; }

    for (int k0 = 0; k0 < K; k0 += 32) {
        async_copy16(gB0, ldsB0);
        async_copy16(gB1, ldsB1);
        gB0 += 32; gB1 += 32;
        uint4 w0 = make_uint4(pk2(f0.x, f0.y), pk2(f0.z, f0.w),
                              pk2(f1.x, f1.y), pk2(f1.z, f1.w));
        uint4 w1 = make_uint4(pk2(f2.x, f2.y), pk2(f2.z, f2.w),
                              pk2(f3.x, f3.y), pk2(f3.z, f3.w));
        *(uint4*)wp       = w0;
        *(uint4*)(wp + 8) = w1;
        __syncthreads();                       // drains B async + A ds_writes

        const int kn = k0 + 32;                // prefetch next A tile (hidden
        if (kn < K) {                          // under MFMA; drained at bar2)
            const float* Ab = (kn < 512) ? states : actions;
            const float4* g = (const float4*)(Ab + rowOff + (kn & 511));
            f0 = g[0]; f1 = g[1]; f2 = g[2]; f3 = g[3];
        }

        frag_ab af[4], bfr[4];
#pragma unroll
        for (int i = 0; i < 4; i++)
            af[i] = *(const frag_ab*)&As[(wm + i * 16 + lrow) * 40 + quad * 8];
#pragma unroll
        for (int j = 0; j < 4; j++)
            bfr[j] = *(const frag_ab*)&Bs[(wn + j * 16 + lrow) * 32 + quad * 8];
#pragma unroll
        for (int i = 0; i < 4; i++)
#pragma unroll
            for (int j = 0; j < 4; j++)
                acc[i][j] = __builtin_amdgcn_mfma_f32_16x16x32_bf16(
                    af[i], bfr[j], acc[i][j], 0, 0, 0);
        __syncthreads();
    }

    // h1[row][col] = bf16(relu(acc + bias[col]))  (RNE)
#pragma unroll
    for (int j = 0; j < 4; j++) {
        const int col = bn + wn + j * 16 + lrow;
        const float bc = bias[col];
#pragma unroll
        for (int i = 0; i < 4; i++) {
            const int row0 = bm + wm + i * 16 + quad * 4;
#pragma unroll
            for (int r = 0; r < 4; r++) {
                float v = acc[i][j][r] + bc;
                v = v > 0.0f ? v : 0.0f;
                H[(size_t)(row0 + r) * EMBED + col] = f2bf(v);
            }
        }
    }
}

// ---------------------------------------------------------------------------
// Layer 2+3 (Q and V in one launch): out[row] += sum_n relu(h1@W2 + b2)*w3[n]
// Pure m97 structure (A is bf16 h1), fused layer-3 epilogue with atomics.
// ---------------------------------------------------------------------------
__global__ __launch_bounds__(256)
void layer2(const unsigned short* __restrict__ h1Q,
            const unsigned short* __restrict__ h1V,
            const unsigned short* __restrict__ Qw2t,
            const unsigned short* __restrict__ Vw2t,
            const float* __restrict__ Qb2, const float* __restrict__ Vb2,
            const float* __restrict__ Qw3, const float* __restrict__ Vw3,
            float* __restrict__ out) {
    __shared__ __align__(16) unsigned short As[128 * 32];   // 8 KB
    __shared__ __align__(16) unsigned short Bs[128 * 32];   // 8 KB

    const int tid = threadIdx.x, wave = tid >> 6, lane = tid & 63;
    const bool isV = blockIdx.x >= 4;
    const int bn = (blockIdx.x & 3) * 128;
    const int bm = blockIdx.y * 128;
    const unsigned short* A  = isV ? h1V : h1Q;
    const unsigned short* Wt = isV ? Vw2t : Qw2t;
    const float* bias = isV ? Vb2 : Qb2;
    const float* w3   = isV ? Vw3 : Qw3;
    float* op = out + (isV ? ROWS : 0);

    const int wm = (wave & 1) * 64, wn = (wave >> 1) * 64;
    const int lrow = lane & 15, quad = lane >> 4;
    f32x4 acc[4][4] = {};

    const int lin  = wave * 1024 + lane * 16;
    const int rowS = lin >> 6, colS = (lin & 63) >> 1;
    const unsigned short* gA0 = A  + (size_t)(bm + rowS)      * 512 + colS;
    const unsigned short* gA1 = A  + (size_t)(bm + rowS + 64) * 512 + colS;
    const unsigned short* gB0 = Wt + (size_t)(bn + rowS)      * 512 + colS;
    const unsigned short* gB1 = Wt + (size_t)(bn + rowS + 64) * 512 + colS;
    unsigned short* ldsA0 = As + wave * 512;
    unsigned short* ldsA1 = As + 2048 + wave * 512;
    unsigned short* ldsB0 = Bs + wave * 512;
    unsigned short* ldsB1 = Bs + 2048 + wave * 512;

    for (int k0 = 0; k0 < 512; k0 += 32) {
        async_copy16(gA0, ldsA0);
        async_copy16(gA1, ldsA1);
        async_copy16(gB0, ldsB0);
        async_copy16(gB1, ldsB1);
        gA0 += 32; gA1 += 32; gB0 += 32; gB1 += 32;
        __syncthreads();

        frag_ab af[4], bfr[4];
#pragma unroll
        for (int i = 0; i < 4; i++)
            af[i] = *(const frag_ab*)&As[(wm + i * 16 + lrow) * 32 + quad * 8];
#pragma unroll
        for (int j = 0; j < 4; j++)
            bfr[j] = *(const frag_ab*)&Bs[(wn + j * 16 + lrow) * 32 + quad * 8];
#pragma unroll
        for (int i = 0; i < 4; i++)
#pragma unroll
            for (int j = 0; j < 4; j++)
                acc[i][j] = __builtin_amdgcn_mfma_f32_16x16x32_bf16(
                    af[i], bfr[j], acc[i][j], 0, 0, 0);
        __syncthreads();
    }

    // fused layer 3: out[row] += sum_cols relu(acc + bias) * w3[col]
    float bc[4], wc[4];
#pragma unroll
    for (int j = 0; j < 4; j++) {
        const int col = bn + wn + j * 16 + lrow;
        bc[j] = bias[col];
        wc[j] = w3[col];
    }
#pragma unroll
    for (int i = 0; i < 4; i++) {
#pragma unroll
        for (int r = 0; r < 4; r++) {
            float s = 0.0f;
#pragma unroll
            for (int j = 0; j < 4; j++) {
                float v = acc[i][j][r] + bc[j];
                v = v > 0.0f ? v : 0.0f;
                s += v * wc[j];
            }
#pragma unroll
            for (int m = 1; m < 16; m <<= 1) s += __shfl_xor(s, m, 64);
            if (lrow == 0)
                atomicAdd(&op[bm + wm + i * 16 + quad * 4 + r], s);
        }
    }
}

extern "C" void kernel_launch(void* const* d_in, const int* in_sizes, int n_in,
                              void* d_out, int out_size, void* d_ws, size_t ws_size,
                              hipStream_t stream) {
    const float* states  = (const float*)d_in[0];
    const float* actions = (const float*)d_in[1];
    const float* Qw1 = (const float*)d_in[2];
    const float* Qb1 = (const float*)d_in[3];
    const float* Qw2 = (const float*)d_in[4];
    const float* Qb2 = (const float*)d_in[5];
    const float* Qw3 = (const float*)d_in[6];
    const float* Qb3 = (const float*)d_in[7];
    const float* Vw1 = (const float*)d_in[8];
    const float* Vb1 = (const float*)d_in[9];
    const float* Vw2 = (const float*)d_in[10];
    const float* Vb2 = (const float*)d_in[11];
    const float* Vw3 = (const float*)d_in[12];
    const float* Vb3 = (const float*)d_in[13];
    float* out = (float*)d_out;

    // workspace layout (bytes)
    char* ws = (char*)d_ws;
    unsigned short* h1Q  = (unsigned short*)ws;                        // 32 MB
    unsigned short* h1V  = (unsigned short*)(ws + 33554432);           // 32 MB
    unsigned short* Qw1t = (unsigned short*)(ws + 67108864);           // 1 MB
    unsigned short* Qw2t = Qw1t + 512 * 1024;                          // 512 KB
    unsigned short* Vw1t = Qw2t + 512 * 512;
    unsigned short* Vw2t = Vw1t + 512 * 512;

    init_out<<<dim3(256), dim3(256), 0, stream>>>(out, Qb3, Vb3);
    prep_w<<<dim3(5120), dim3(256), 0, stream>>>(Qw1, Qw2, Vw1, Vw2,
                                                 Qw1t, Qw2t, Vw1t, Vw2t);

    dim3 grid(8, ROWS / 128);   // x: 0-3 = Q n-blocks, 4-7 = V n-blocks
    layer1<<<grid, 256, 0, stream>>>(states, actions, Qw1t, Vw1t,
                                     Qb1, Vb1, h1Q, h1V);
    layer2<<<grid, 256, 0, stream>>>(h1Q, h1V, Qw2t, Vw2t,
                                     Qb2, Vb2, Qw3, Vw3, out);
}

// Round 3
// 337.794 us; speedup vs baseline: 1.0420x; 1.0420x over previous
//
#include <hip/hip_runtime.h>

// ---------------------------------------------------------------------------
// QTranBase: twin 3-layer MLPs via bf16 MFMA.
// R3: convert-once (R1 core restored; R2's register A-prefetch was
// latency-bound at MfmaUtil 12%). Fixes: fused prep kernel (convert 32
// elems/thread for ILP + weight transpose + out init in one launch),
// Q+V merged per GEMM layer, m97 staging geometry untouched.
// ---------------------------------------------------------------------------

#define ROWS 32768
#define EMBED 512

using frag_ab = __attribute__((ext_vector_type(8))) short;   // 8 x bf16
using f32x4   = __attribute__((ext_vector_type(4))) float;   // MFMA C/D

__device__ __forceinline__ unsigned short f2bf(float f) {
    // round-to-nearest-even
    unsigned int u = __builtin_bit_cast(unsigned int, f);
    return (unsigned short)((u + 0x7fffu + ((u >> 16) & 1u)) >> 16);
}

__device__ __forceinline__ unsigned pk2rne(float lo, float hi) {
    return (unsigned)f2bf(lo) | ((unsigned)f2bf(hi) << 16);
}

__device__ __forceinline__ void async_copy16(const void* g, void* l) {
    // dest = wave-uniform LDS base; HW writes base + lane*16
    __builtin_amdgcn_global_load_lds(
        (const __attribute__((address_space(1))) unsigned int*)g,
        (__attribute__((address_space(3))) unsigned int*)l, 16, 0, 0);
}

// ---------------------------------------------------------------------------
// Fused prep: blocks [0,4096) convert X; [4096,4736) transpose weights;
// [4736,4992) seed out with layer-3 bias.
// ---------------------------------------------------------------------------
__global__ __launch_bounds__(256)
void prep(const float* __restrict__ states, const float* __restrict__ actions,
          const float* __restrict__ Qw1, const float* __restrict__ Qw2,
          const float* __restrict__ Vw1, const float* __restrict__ Vw2,
          const float* __restrict__ qb3, const float* __restrict__ vb3,
          unsigned short* __restrict__ X,
          unsigned short* __restrict__ Qw1t, unsigned short* __restrict__ Qw2t,
          unsigned short* __restrict__ Vw1t, unsigned short* __restrict__ Vw2t,
          float* __restrict__ out) {
    const int b = blockIdx.x, tid = threadIdx.x;
    if (b < 4096) {
        // X[m][0:512]=bf16(states[m]); X[m][512:1024]=bf16(actions[m])
        // 32 elems/thread: 8 independent float4 loads, then 4 uint4 stores.
        int c = b * 256 + tid;            // chunk of 32 within one row
        int m = c >> 5, col = (c & 31) * 32;
        const float* src = (col < 512) ? states + (size_t)m * 512 + col
                                       : actions + (size_t)m * 512 + (col - 512);
        float4 f[8];
#pragma unroll
        for (int i = 0; i < 8; i++) f[i] = ((const float4*)src)[i];
        uint4* dst = (uint4*)(X + (size_t)m * 1024 + col);
#pragma unroll
        for (int i = 0; i < 4; i++)
            dst[i] = make_uint4(pk2rne(f[2*i].x,   f[2*i].y),
                                pk2rne(f[2*i].z,   f[2*i].w),
                                pk2rne(f[2*i+1].x, f[2*i+1].y),
                                pk2rne(f[2*i+1].z, f[2*i+1].w));
    } else if (b < 4736) {
        // Wt[n][k] = bf16(W[k][n]); 8 k per thread (gather-read, uint4 store)
        int g = (b - 4096) * 256 + tid;
        const float* W; unsigned short* O; int n, k0, ldo;
        if (g < 65536) {                  // Qw1: [1024][512] -> [512][1024]
            int o = g * 8; n = o >> 10; k0 = o & 1023; W = Qw1; O = Qw1t; ldo = 1024;
        } else {
            g -= 65536;
            int seg = g >> 15, r = g & 32767, o = r * 8;
            n = o >> 9; k0 = o & 511; ldo = 512;
            W = (seg == 0) ? Qw2 : (seg == 1) ? Vw1 : Vw2;
            O = (seg == 0) ? Qw2t : (seg == 1) ? Vw1t : Vw2t;
        }
        float v[8];
#pragma unroll
        for (int j = 0; j < 8; j++) v[j] = W[(size_t)(k0 + j) * 512 + n];
        *(uint4*)(O + (size_t)n * ldo + k0) =
            make_uint4(pk2rne(v[0], v[1]), pk2rne(v[2], v[3]),
                       pk2rne(v[4], v[5]), pk2rne(v[6], v[7]));
    } else {
        // out[i] = (i < ROWS) ? Qb3 : Vb3  (layer-3 bias pre-seed for atomics)
        int i = (b - 4736) * 256 + tid;
        out[i] = (i < ROWS) ? qb3[0] : vb3[0];
    }
}

// ---------------------------------------------------------------------------
// Layer 1 (Q+V): h1 = relu(X @ Wt^T + bias). blockIdx.x<4 -> Q (K=1024),
// >=4 -> V (K=512, first 512 cols of X). Pure m97 staging.
// ---------------------------------------------------------------------------
__global__ __launch_bounds__(256)
void layer1(const unsigned short* __restrict__ X,
            const unsigned short* __restrict__ Qw1t,
            const unsigned short* __restrict__ Vw1t,
            const float* __restrict__ Qb1, const float* __restrict__ Vb1,
            unsigned short* __restrict__ h1Q, unsigned short* __restrict__ h1V) {
    __shared__ __align__(16) unsigned short As[128 * 32];   // 8 KB
    __shared__ __align__(16) unsigned short Bs[128 * 32];   // 8 KB

    const int tid = threadIdx.x, wave = tid >> 6, lane = tid & 63;
    const bool isV = blockIdx.x >= 4;
    const int bn = (blockIdx.x & 3) * 128;
    const int bm = blockIdx.y * 128;
    const int K = isV ? 512 : 1024;           // ldb == K for both weights
    const unsigned short* Wt = isV ? Vw1t : Qw1t;
    const float* bias = isV ? Vb1 : Qb1;
    unsigned short* H = isV ? h1V : h1Q;

    const int wm = (wave & 1) * 64, wn = (wave >> 1) * 64;
    const int lrow = lane & 15, quad = lane >> 4;
    f32x4 acc[4][4] = {};

    const int lin  = wave * 1024 + lane * 16;
    const int rowS = lin >> 6, colS = (lin & 63) >> 1;
    const unsigned short* gA0 = X  + (size_t)(bm + rowS)      * 1024 + colS;
    const unsigned short* gA1 = X  + (size_t)(bm + rowS + 64) * 1024 + colS;
    const unsigned short* gB0 = Wt + (size_t)(bn + rowS)      * K + colS;
    const unsigned short* gB1 = Wt + (size_t)(bn + rowS + 64) * K + colS;
    unsigned short* ldsA0 = As + wave * 512;
    unsigned short* ldsA1 = As + 2048 + wave * 512;
    unsigned short* ldsB0 = Bs + wave * 512;
    unsigned short* ldsB1 = Bs + 2048 + wave * 512;

    for (int k0 = 0; k0 < K; k0 += 32) {
        async_copy16(gA0, ldsA0);
        async_copy16(gA1, ldsA1);
        async_copy16(gB0, ldsB0);
        async_copy16(gB1, ldsB1);
        gA0 += 32; gA1 += 32; gB0 += 32; gB1 += 32;
        __syncthreads();

        frag_ab af[4], bfr[4];
#pragma unroll
        for (int i = 0; i < 4; i++)
            af[i] = *(const frag_ab*)&As[(wm + i * 16 + lrow) * 32 + quad * 8];
#pragma unroll
        for (int j = 0; j < 4; j++)
            bfr[j] = *(const frag_ab*)&Bs[(wn + j * 16 + lrow) * 32 + quad * 8];
#pragma unroll
        for (int i = 0; i < 4; i++)
#pragma unroll
            for (int j = 0; j < 4; j++)
                acc[i][j] = __builtin_amdgcn_mfma_f32_16x16x32_bf16(
                    af[i], bfr[j], acc[i][j], 0, 0, 0);
        __syncthreads();
    }

    // h1[row][col] = bf16(relu(acc + bias[col]))
#pragma unroll
    for (int j = 0; j < 4; j++) {
        const int col = bn + wn + j * 16 + lrow;
        const float bc = bias[col];
#pragma unroll
        for (int i = 0; i < 4; i++) {
            const int row0 = bm + wm + i * 16 + quad * 4;
#pragma unroll
            for (int r = 0; r < 4; r++) {
                float v = acc[i][j][r] + bc;
                v = v > 0.0f ? v : 0.0f;
                H[(size_t)(row0 + r) * EMBED + col] = f2bf(v);
            }
        }
    }
}

// ---------------------------------------------------------------------------
// Layer 2+3 (Q+V): out[row] += sum_n relu(h1 @ W2^T + b2)[n] * w3[n]
// ---------------------------------------------------------------------------
__global__ __launch_bounds__(256)
void layer2(const unsigned short* __restrict__ h1Q,
            const unsigned short* __restrict__ h1V,
            const unsigned short* __restrict__ Qw2t,
            const unsigned short* __restrict__ Vw2t,
            const float* __restrict__ Qb2, const float* __restrict__ Vb2,
            const float* __restrict__ Qw3, const float* __restrict__ Vw3,
            float* __restrict__ out) {
    __shared__ __align__(16) unsigned short As[128 * 32];
    __shared__ __align__(16) unsigned short Bs[128 * 32];

    const int tid = threadIdx.x, wave = tid >> 6, lane = tid & 63;
    const bool isV = blockIdx.x >= 4;
    const int bn = (blockIdx.x & 3) * 128;
    const int bm = blockIdx.y * 128;
    const unsigned short* A  = isV ? h1V : h1Q;
    const unsigned short* Wt = isV ? Vw2t : Qw2t;
    const float* bias = isV ? Vb2 : Qb2;
    const float* w3   = isV ? Vw3 : Qw3;
    float* op = out + (isV ? ROWS : 0);

    const int wm = (wave & 1) * 64, wn = (wave >> 1) * 64;
    const int lrow = lane & 15, quad = lane >> 4;
    f32x4 acc[4][4] = {};

    const int lin  = wave * 1024 + lane * 16;
    const int rowS = lin >> 6, colS = (lin & 63) >> 1;
    const unsigned short* gA0 = A  + (size_t)(bm + rowS)      * 512 + colS;
    const unsigned short* gA1 = A  + (size_t)(bm + rowS + 64) * 512 + colS;
    const unsigned short* gB0 = Wt + (size_t)(bn + rowS)      * 512 + colS;
    const unsigned short* gB1 = Wt + (size_t)(bn + rowS + 64) * 512 + colS;
    unsigned short* ldsA0 = As + wave * 512;
    unsigned short* ldsA1 = As + 2048 + wave * 512;
    unsigned short* ldsB0 = Bs + wave * 512;
    unsigned short* ldsB1 = Bs + 2048 + wave * 512;

    for (int k0 = 0; k0 < 512; k0 += 32) {
        async_copy16(gA0, ldsA0);
        async_copy16(gA1, ldsA1);
        async_copy16(gB0, ldsB0);
        async_copy16(gB1, ldsB1);
        gA0 += 32; gA1 += 32; gB0 += 32; gB1 += 32;
        __syncthreads();

        frag_ab af[4], bfr[4];
#pragma unroll
        for (int i = 0; i < 4; i++)
            af[i] = *(const frag_ab*)&As[(wm + i * 16 + lrow) * 32 + quad * 8];
#pragma unroll
        for (int j = 0; j < 4; j++)
            bfr[j] = *(const frag_ab*)&Bs[(wn + j * 16 + lrow) * 32 + quad * 8];
#pragma unroll
        for (int i = 0; i < 4; i++)
#pragma unroll
            for (int j = 0; j < 4; j++)
                acc[i][j] = __builtin_amdgcn_mfma_f32_16x16x32_bf16(
                    af[i], bfr[j], acc[i][j], 0, 0, 0);
        __syncthreads();
    }

    float bc[4], wc[4];
#pragma unroll
    for (int j = 0; j < 4; j++) {
        const int col = bn + wn + j * 16 + lrow;
        bc[j] = bias[col];
        wc[j] = w3[col];
    }
#pragma unroll
    for (int i = 0; i < 4; i++) {
#pragma unroll
        for (int r = 0; r < 4; r++) {
            float s = 0.0f;
#pragma unroll
            for (int j = 0; j < 4; j++) {
                float v = acc[i][j][r] + bc[j];
                v = v > 0.0f ? v : 0.0f;
                s += v * wc[j];
            }
#pragma unroll
            for (int m = 1; m < 16; m <<= 1) s += __shfl_xor(s, m, 64);
            if (lrow == 0)
                atomicAdd(&op[bm + wm + i * 16 + quad * 4 + r], s);
        }
    }
}

extern "C" void kernel_launch(void* const* d_in, const int* in_sizes, int n_in,
                              void* d_out, int out_size, void* d_ws, size_t ws_size,
                              hipStream_t stream) {
    const float* states  = (const float*)d_in[0];
    const float* actions = (const float*)d_in[1];
    const float* Qw1 = (const float*)d_in[2];
    const float* Qb1 = (const float*)d_in[3];
    const float* Qw2 = (const float*)d_in[4];
    const float* Qb2 = (const float*)d_in[5];
    const float* Qw3 = (const float*)d_in[6];
    const float* Qb3 = (const float*)d_in[7];
    const float* Vw1 = (const float*)d_in[8];
    const float* Vb1 = (const float*)d_in[9];
    const float* Vw2 = (const float*)d_in[10];
    const float* Vb2 = (const float*)d_in[11];
    const float* Vw3 = (const float*)d_in[12];
    const float* Vb3 = (const float*)d_in[13];
    float* out = (float*)d_out;

    // workspace layout (bytes)
    char* ws = (char*)d_ws;
    unsigned short* X    = (unsigned short*)ws;                        // 64 MB
    unsigned short* h1Q  = (unsigned short*)(ws + 67108864);           // 32 MB
    unsigned short* h1V  = (unsigned short*)(ws + 100663296);          // 32 MB
    unsigned short* Qw1t = (unsigned short*)(ws + 134217728);          // 1 MB
    unsigned short* Qw2t = Qw1t + 512 * 1024;
    unsigned short* Vw1t = Qw2t + 512 * 512;
    unsigned short* Vw2t = Vw1t + 512 * 512;

    prep<<<dim3(4992), dim3(256), 0, stream>>>(states, actions, Qw1, Qw2, Vw1, Vw2,
                                               Qb3, Vb3, X, Qw1t, Qw2t, Vw1t, Vw2t, out);

    dim3 grid(8, ROWS / 128);   // x: 0-3 = Q n-blocks, 4-7 = V n-blocks
    layer1<<<grid, 256, 0, stream>>>(X, Qw1t, Vw1t, Qb1, Vb1, h1Q, h1V);
    layer2<<<grid, 256, 0, stream>>>(h1Q, h1V, Qw2t, Vw2t, Qb2, Vb2, Qw3, Vw3, out);
}

// Round 4
// 336.529 us; speedup vs baseline: 1.0459x; 1.0038x over previous
//
#include <hip/hip_runtime.h>

// ---------------------------------------------------------------------------
// QTranBase: twin 3-layer MLPs via bf16 MFMA.
// R4: BK=64 via two m97-style 8KB k-half sub-tiles per operand (keeps the
// verified 64B-row LDS geometry; a flat 128B row would 16-way bank-conflict
// the frag reads). Halves barrier drains: 32 MFMA/wave per drain vs 16.
// Frags consumed per k-half sequentially to hold VGPR at m97 levels.
// ---------------------------------------------------------------------------

#define ROWS 32768
#define EMBED 512

using frag_ab = __attribute__((ext_vector_type(8))) short;   // 8 x bf16
using f32x4   = __attribute__((ext_vector_type(4))) float;   // MFMA C/D

__device__ __forceinline__ unsigned short f2bf(float f) {
    unsigned int u = __builtin_bit_cast(unsigned int, f);
    return (unsigned short)((u + 0x7fffu + ((u >> 16) & 1u)) >> 16);
}

__device__ __forceinline__ unsigned pk2rne(float lo, float hi) {
    return (unsigned)f2bf(lo) | ((unsigned)f2bf(hi) << 16);
}

__device__ __forceinline__ void async_copy16(const void* g, void* l) {
    // dest = wave-uniform LDS base; HW writes base + lane*16
    __builtin_amdgcn_global_load_lds(
        (const __attribute__((address_space(1))) unsigned int*)g,
        (__attribute__((address_space(3))) unsigned int*)l, 16, 0, 0);
}

// ---------------------------------------------------------------------------
// Fused prep: blocks [0,4096) convert X; [4096,4736) transpose weights;
// [4736,4992) seed out with layer-3 bias.
// ---------------------------------------------------------------------------
__global__ __launch_bounds__(256)
void prep(const float* __restrict__ states, const float* __restrict__ actions,
          const float* __restrict__ Qw1, const float* __restrict__ Qw2,
          const float* __restrict__ Vw1, const float* __restrict__ Vw2,
          const float* __restrict__ qb3, const float* __restrict__ vb3,
          unsigned short* __restrict__ X,
          unsigned short* __restrict__ Qw1t, unsigned short* __restrict__ Qw2t,
          unsigned short* __restrict__ Vw1t, unsigned short* __restrict__ Vw2t,
          float* __restrict__ out) {
    const int b = blockIdx.x, tid = threadIdx.x;
    if (b < 4096) {
        int c = b * 256 + tid;            // chunk of 32 within one row
        int m = c >> 5, col = (c & 31) * 32;
        const float* src = (col < 512) ? states + (size_t)m * 512 + col
                                       : actions + (size_t)m * 512 + (col - 512);
        float4 f[8];
#pragma unroll
        for (int i = 0; i < 8; i++) f[i] = ((const float4*)src)[i];
        uint4* dst = (uint4*)(X + (size_t)m * 1024 + col);
#pragma unroll
        for (int i = 0; i < 4; i++)
            dst[i] = make_uint4(pk2rne(f[2*i].x,   f[2*i].y),
                                pk2rne(f[2*i].z,   f[2*i].w),
                                pk2rne(f[2*i+1].x, f[2*i+1].y),
                                pk2rne(f[2*i+1].z, f[2*i+1].w));
    } else if (b < 4736) {
        int g = (b - 4096) * 256 + tid;
        const float* W; unsigned short* O; int n, k0, ldo;
        if (g < 65536) {                  // Qw1: [1024][512] -> [512][1024]
            int o = g * 8; n = o >> 10; k0 = o & 1023; W = Qw1; O = Qw1t; ldo = 1024;
        } else {
            g -= 65536;
            int seg = g >> 15, r = g & 32767, o = r * 8;
            n = o >> 9; k0 = o & 511; ldo = 512;
            W = (seg == 0) ? Qw2 : (seg == 1) ? Vw1 : Vw2;
            O = (seg == 0) ? Qw2t : (seg == 1) ? Vw1t : Vw2t;
        }
        float v[8];
#pragma unroll
        for (int j = 0; j < 8; j++) v[j] = W[(size_t)(k0 + j) * 512 + n];
        *(uint4*)(O + (size_t)n * ldo + k0) =
            make_uint4(pk2rne(v[0], v[1]), pk2rne(v[2], v[3]),
                       pk2rne(v[4], v[5]), pk2rne(v[6], v[7]));
    } else {
        int i = (b - 4736) * 256 + tid;
        out[i] = (i < ROWS) ? qb3[0] : vb3[0];
    }
}

// ---------------------------------------------------------------------------
// Layer 1 (Q+V): h1 = relu(X @ Wt^T + bias). blockIdx.x<4 -> Q (K=1024),
// >=4 -> V (K=512, first 512 cols of X). BK=64 as two 32-wide sub-tiles.
// ---------------------------------------------------------------------------
__global__ __launch_bounds__(256)
void layer1(const unsigned short* __restrict__ X,
            const unsigned short* __restrict__ Qw1t,
            const unsigned short* __restrict__ Vw1t,
            const float* __restrict__ Qb1, const float* __restrict__ Vb1,
            unsigned short* __restrict__ h1Q, unsigned short* __restrict__ h1V) {
    __shared__ __align__(16) unsigned short As[2 * 4096];   // 16 KB (2 k-halves)
    __shared__ __align__(16) unsigned short Bs[2 * 4096];   // 16 KB

    const int tid = threadIdx.x, wave = tid >> 6, lane = tid & 63;
    const bool isV = blockIdx.x >= 4;
    const int bn = (blockIdx.x & 3) * 128;
    const int bm = blockIdx.y * 128;
    const int K = isV ? 512 : 1024;           // ldb == K for both weights
    const unsigned short* Wt = isV ? Vw1t : Qw1t;
    const float* bias = isV ? Vb1 : Qb1;
    unsigned short* H = isV ? h1V : h1Q;

    const int wm = (wave & 1) * 64, wn = (wave >> 1) * 64;
    const int lrow = lane & 15, quad = lane >> 4;
    f32x4 acc[4][4] = {};

    const int lin  = wave * 1024 + lane * 16;
    const int rowS = lin >> 6, colS = (lin & 63) >> 1;
    const unsigned short* gA0 = X  + (size_t)(bm + rowS)      * 1024 + colS;
    const unsigned short* gA1 = X  + (size_t)(bm + rowS + 64) * 1024 + colS;
    const unsigned short* gB0 = Wt + (size_t)(bn + rowS)      * K + colS;
    const unsigned short* gB1 = Wt + (size_t)(bn + rowS + 64) * K + colS;
    unsigned short* ldsA0 = As + wave * 512;           // k-half 0
    unsigned short* ldsA1 = As + 2048 + wave * 512;
    unsigned short* ldsB0 = Bs + wave * 512;
    unsigned short* ldsB1 = Bs + 2048 + wave * 512;

    for (int k0 = 0; k0 < K; k0 += 64) {
        // k-half 0 -> sub-buffer 0, k-half 1 -> sub-buffer +4096
        async_copy16(gA0,      ldsA0);
        async_copy16(gA0 + 32, ldsA0 + 4096);
        async_copy16(gA1,      ldsA1);
        async_copy16(gA1 + 32, ldsA1 + 4096);
        async_copy16(gB0,      ldsB0);
        async_copy16(gB0 + 32, ldsB0 + 4096);
        async_copy16(gB1,      ldsB1);
        async_copy16(gB1 + 32, ldsB1 + 4096);
        gA0 += 64; gA1 += 64; gB0 += 64; gB1 += 64;
        __syncthreads();

#pragma unroll
        for (int s = 0; s < 2; s++) {
            frag_ab af[4], bfr[4];
#pragma unroll
            for (int i = 0; i < 4; i++)
                af[i] = *(const frag_ab*)&As[s * 4096 + (wm + i * 16 + lrow) * 32 + quad * 8];
#pragma unroll
            for (int j = 0; j < 4; j++)
                bfr[j] = *(const frag_ab*)&Bs[s * 4096 + (wn + j * 16 + lrow) * 32 + quad * 8];
#pragma unroll
            for (int i = 0; i < 4; i++)
#pragma unroll
                for (int j = 0; j < 4; j++)
                    acc[i][j] = __builtin_amdgcn_mfma_f32_16x16x32_bf16(
                        af[i], bfr[j], acc[i][j], 0, 0, 0);
        }
        __syncthreads();
    }

    // h1[row][col] = bf16(relu(acc + bias[col]))
#pragma unroll
    for (int j = 0; j < 4; j++) {
        const int col = bn + wn + j * 16 + lrow;
        const float bc = bias[col];
#pragma unroll
        for (int i = 0; i < 4; i++) {
            const int row0 = bm + wm + i * 16 + quad * 4;
#pragma unroll
            for (int r = 0; r < 4; r++) {
                float v = acc[i][j][r] + bc;
                v = v > 0.0f ? v : 0.0f;
                H[(size_t)(row0 + r) * EMBED + col] = f2bf(v);
            }
        }
    }
}

// ---------------------------------------------------------------------------
// Layer 2+3 (Q+V): out[row] += sum_n relu(h1 @ W2^T + b2)[n] * w3[n]
// ---------------------------------------------------------------------------
__global__ __launch_bounds__(256)
void layer2(const unsigned short* __restrict__ h1Q,
            const unsigned short* __restrict__ h1V,
            const unsigned short* __restrict__ Qw2t,
            const unsigned short* __restrict__ Vw2t,
            const float* __restrict__ Qb2, const float* __restrict__ Vb2,
            const float* __restrict__ Qw3, const float* __restrict__ Vw3,
            float* __restrict__ out) {
    __shared__ __align__(16) unsigned short As[2 * 4096];
    __shared__ __align__(16) unsigned short Bs[2 * 4096];

    const int tid = threadIdx.x, wave = tid >> 6, lane = tid & 63;
    const bool isV = blockIdx.x >= 4;
    const int bn = (blockIdx.x & 3) * 128;
    const int bm = blockIdx.y * 128;
    const unsigned short* A  = isV ? h1V : h1Q;
    const unsigned short* Wt = isV ? Vw2t : Qw2t;
    const float* bias = isV ? Vb2 : Qb2;
    const float* w3   = isV ? Vw3 : Qw3;
    float* op = out + (isV ? ROWS : 0);

    const int wm = (wave & 1) * 64, wn = (wave >> 1) * 64;
    const int lrow = lane & 15, quad = lane >> 4;
    f32x4 acc[4][4] = {};

    const int lin  = wave * 1024 + lane * 16;
    const int rowS = lin >> 6, colS = (lin & 63) >> 1;
    const unsigned short* gA0 = A  + (size_t)(bm + rowS)      * 512 + colS;
    const unsigned short* gA1 = A  + (size_t)(bm + rowS + 64) * 512 + colS;
    const unsigned short* gB0 = Wt + (size_t)(bn + rowS)      * 512 + colS;
    const unsigned short* gB1 = Wt + (size_t)(bn + rowS + 64) * 512 + colS;
    unsigned short* ldsA0 = As + wave * 512;
    unsigned short* ldsA1 = As + 2048 + wave * 512;
    unsigned short* ldsB0 = Bs + wave * 512;
    unsigned short* ldsB1 = Bs + 2048 + wave * 512;

    for (int k0 = 0; k0 < 512; k0 += 64) {
        async_copy16(gA0,      ldsA0);
        async_copy16(gA0 + 32, ldsA0 + 4096);
        async_copy16(gA1,      ldsA1);
        async_copy16(gA1 + 32, ldsA1 + 4096);
        async_copy16(gB0,      ldsB0);
        async_copy16(gB0 + 32, ldsB0 + 4096);
        async_copy16(gB1,      ldsB1);
        async_copy16(gB1 + 32, ldsB1 + 4096);
        gA0 += 64; gA1 += 64; gB0 += 64; gB1 += 64;
        __syncthreads();

#pragma unroll
        for (int s = 0; s < 2; s++) {
            frag_ab af[4], bfr[4];
#pragma unroll
            for (int i = 0; i < 4; i++)
                af[i] = *(const frag_ab*)&As[s * 4096 + (wm + i * 16 + lrow) * 32 + quad * 8];
#pragma unroll
            for (int j = 0; j < 4; j++)
                bfr[j] = *(const frag_ab*)&Bs[s * 4096 + (wn + j * 16 + lrow) * 32 + quad * 8];
#pragma unroll
            for (int i = 0; i < 4; i++)
#pragma unroll
                for (int j = 0; j < 4; j++)
                    acc[i][j] = __builtin_amdgcn_mfma_f32_16x16x32_bf16(
                        af[i], bfr[j], acc[i][j], 0, 0, 0);
        }
        __syncthreads();
    }

    float bc[4], wc[4];
#pragma unroll
    for (int j = 0; j < 4; j++) {
        const int col = bn + wn + j * 16 + lrow;
        bc[j] = bias[col];
        wc[j] = w3[col];
    }
#pragma unroll
    for (int i = 0; i < 4; i++) {
#pragma unroll
        for (int r = 0; r < 4; r++) {
            float s = 0.0f;
#pragma unroll
            for (int j = 0; j < 4; j++) {
                float v = acc[i][j][r] + bc[j];
                v = v > 0.0f ? v : 0.0f;
                s += v * wc[j];
            }
#pragma unroll
            for (int m = 1; m < 16; m <<= 1) s += __shfl_xor(s, m, 64);
            if (lrow == 0)
                atomicAdd(&op[bm + wm + i * 16 + quad * 4 + r], s);
        }
    }
}

extern "C" void kernel_launch(void* const* d_in, const int* in_sizes, int n_in,
                              void* d_out, int out_size, void* d_ws, size_t ws_size,
                              hipStream_t stream) {
    const float* states  = (const float*)d_in[0];
    const float* actions = (const float*)d_in[1];
    const float* Qw1 = (const float*)d_in[2];
    const float* Qb1 = (const float*)d_in[3];
    const float* Qw2 = (const float*)d_in[4];
    const float* Qb2 = (const float*)d_in[5];
    const float* Qw3 = (const float*)d_in[6];
    const float* Qb3 = (const float*)d_in[7];
    const float* Vw1 = (const float*)d_in[8];
    const float* Vb1 = (const float*)d_in[9];
    const float* Vw2 = (const float*)d_in[10];
    const float* Vb2 = (const float*)d_in[11];
    const float* Vw3 = (const float*)d_in[12];
    const float* Vb3 = (const float*)d_in[13];
    float* out = (float*)d_out;

    // workspace layout (bytes)
    char* ws = (char*)d_ws;
    unsigned short* X    = (unsigned short*)ws;                        // 64 MB
    unsigned short* h1Q  = (unsigned short*)(ws + 67108864);           // 32 MB
    unsigned short* h1V  = (unsigned short*)(ws + 100663296);          // 32 MB
    unsigned short* Qw1t = (unsigned short*)(ws + 134217728);          // 1 MB
    unsigned short* Qw2t = Qw1t + 512 * 1024;
    unsigned short* Vw1t = Qw2t + 512 * 512;
    unsigned short* Vw2t = Vw1t + 512 * 512;

    prep<<<dim3(4992), dim3(256), 0, stream>>>(states, actions, Qw1, Qw2, Vw1, Vw2,
                                               Qb3, Vb3, X, Qw1t, Qw2t, Vw1t, Vw2t, out);

    dim3 grid(8, ROWS / 128);   // x: 0-3 = Q n-blocks, 4-7 = V n-blocks
    layer1<<<grid, 256, 0, stream>>>(X, Qw1t, Vw1t, Qb1, Vb1, h1Q, h1V);
    layer2<<<grid, 256, 0, stream>>>(h1Q, h1V, Qw2t, Vw2t, Qb2, Vb2, Qw3, Vw3, out);
}

// Round 5
// 304.338 us; speedup vs baseline: 1.1565x; 1.1058x over previous
//
#include <hip/hip_runtime.h>

// ---------------------------------------------------------------------------
// QTranBase: twin 3-layer MLPs via bf16 MFMA.
// R5: XCD-locality swizzle. R4 (BK=64) showed barrier count is NOT the
// limiter; FETCH=200MB vs 768MB logical load traffic at ~5 TB/s through
// L3 says we're cache-BW bound. Remap block->(m,n): the 8 blocks sharing
// an A m-tile get linear IDs 8 apart -> same XCD (L%8) and adjacent in
// dispatch order -> A enters one XCD L2 once; B slabs stay L2-resident.
// ---------------------------------------------------------------------------

#define ROWS 32768
#define EMBED 512

using frag_ab = __attribute__((ext_vector_type(8))) short;   // 8 x bf16
using f32x4   = __attribute__((ext_vector_type(4))) float;   // MFMA C/D

__device__ __forceinline__ unsigned short f2bf(float f) {
    unsigned int u = __builtin_bit_cast(unsigned int, f);
    return (unsigned short)((u + 0x7fffu + ((u >> 16) & 1u)) >> 16);
}

__device__ __forceinline__ unsigned pk2rne(float lo, float hi) {
    return (unsigned)f2bf(lo) | ((unsigned)f2bf(hi) << 16);
}

__device__ __forceinline__ void async_copy16(const void* g, void* l) {
    // dest = wave-uniform LDS base; HW writes base + lane*16
    __builtin_amdgcn_global_load_lds(
        (const __attribute__((address_space(1))) unsigned int*)g,
        (__attribute__((address_space(3))) unsigned int*)l, 16, 0, 0);
}

// decode linear block id -> (m-tile 0..255, nq 0..7) with same-m -> same XCD
__device__ __forceinline__ void decode_mn(int L, int& mi, int& nq) {
    nq = (L >> 3) & 7;
    mi = ((L >> 6) << 3) | (L & 7);
}

// ---------------------------------------------------------------------------
// Fused prep: blocks [0,4096) convert X; [4096,4736) transpose weights;
// [4736,4992) seed out with layer-3 bias.
// ---------------------------------------------------------------------------
__global__ __launch_bounds__(256)
void prep(const float* __restrict__ states, const float* __restrict__ actions,
          const float* __restrict__ Qw1, const float* __restrict__ Qw2,
          const float* __restrict__ Vw1, const float* __restrict__ Vw2,
          const float* __restrict__ qb3, const float* __restrict__ vb3,
          unsigned short* __restrict__ X,
          unsigned short* __restrict__ Qw1t, unsigned short* __restrict__ Qw2t,
          unsigned short* __restrict__ Vw1t, unsigned short* __restrict__ Vw2t,
          float* __restrict__ out) {
    const int b = blockIdx.x, tid = threadIdx.x;
    if (b < 4096) {
        int c = b * 256 + tid;            // chunk of 32 within one row
        int m = c >> 5, col = (c & 31) * 32;
        const float* src = (col < 512) ? states + (size_t)m * 512 + col
                                       : actions + (size_t)m * 512 + (col - 512);
        float4 f[8];
#pragma unroll
        for (int i = 0; i < 8; i++) f[i] = ((const float4*)src)[i];
        uint4* dst = (uint4*)(X + (size_t)m * 1024 + col);
#pragma unroll
        for (int i = 0; i < 4; i++)
            dst[i] = make_uint4(pk2rne(f[2*i].x,   f[2*i].y),
                                pk2rne(f[2*i].z,   f[2*i].w),
                                pk2rne(f[2*i+1].x, f[2*i+1].y),
                                pk2rne(f[2*i+1].z, f[2*i+1].w));
    } else if (b < 4736) {
        int g = (b - 4096) * 256 + tid;
        const float* W; unsigned short* O; int n, k0, ldo;
        if (g < 65536) {                  // Qw1: [1024][512] -> [512][1024]
            int o = g * 8; n = o >> 10; k0 = o & 1023; W = Qw1; O = Qw1t; ldo = 1024;
        } else {
            g -= 65536;
            int seg = g >> 15, r = g & 32767, o = r * 8;
            n = o >> 9; k0 = o & 511; ldo = 512;
            W = (seg == 0) ? Qw2 : (seg == 1) ? Vw1 : Vw2;
            O = (seg == 0) ? Qw2t : (seg == 1) ? Vw1t : Vw2t;
        }
        float v[8];
#pragma unroll
        for (int j = 0; j < 8; j++) v[j] = W[(size_t)(k0 + j) * 512 + n];
        *(uint4*)(O + (size_t)n * ldo + k0) =
            make_uint4(pk2rne(v[0], v[1]), pk2rne(v[2], v[3]),
                       pk2rne(v[4], v[5]), pk2rne(v[6], v[7]));
    } else {
        int i = (b - 4736) * 256 + tid;
        out[i] = (i < ROWS) ? qb3[0] : vb3[0];
    }
}

// ---------------------------------------------------------------------------
// Layer 1 (Q+V): h1 = relu(X @ Wt^T + bias). nq<4 -> Q (K=1024),
// >=4 -> V (K=512, first 512 cols of X). BK=64 as two 32-wide sub-tiles.
// ---------------------------------------------------------------------------
__global__ __launch_bounds__(256)
void layer1(const unsigned short* __restrict__ X,
            const unsigned short* __restrict__ Qw1t,
            const unsigned short* __restrict__ Vw1t,
            const float* __restrict__ Qb1, const float* __restrict__ Vb1,
            unsigned short* __restrict__ h1Q, unsigned short* __restrict__ h1V) {
    __shared__ __align__(16) unsigned short As[2 * 4096];   // 16 KB (2 k-halves)
    __shared__ __align__(16) unsigned short Bs[2 * 4096];   // 16 KB

    const int tid = threadIdx.x, wave = tid >> 6, lane = tid & 63;
    int mi, nq; decode_mn(blockIdx.x, mi, nq);
    const bool isV = nq >= 4;
    const int bn = (nq & 3) * 128;
    const int bm = mi * 128;
    const int K = isV ? 512 : 1024;           // ldb == K for both weights
    const unsigned short* Wt = isV ? Vw1t : Qw1t;
    const float* bias = isV ? Vb1 : Qb1;
    unsigned short* H = isV ? h1V : h1Q;

    const int wm = (wave & 1) * 64, wn = (wave >> 1) * 64;
    const int lrow = lane & 15, quad = lane >> 4;
    f32x4 acc[4][4] = {};

    const int lin  = wave * 1024 + lane * 16;
    const int rowS = lin >> 6, colS = (lin & 63) >> 1;
    const unsigned short* gA0 = X  + (size_t)(bm + rowS)      * 1024 + colS;
    const unsigned short* gA1 = X  + (size_t)(bm + rowS + 64) * 1024 + colS;
    const unsigned short* gB0 = Wt + (size_t)(bn + rowS)      * K + colS;
    const unsigned short* gB1 = Wt + (size_t)(bn + rowS + 64) * K + colS;
    unsigned short* ldsA0 = As + wave * 512;           // k-half 0
    unsigned short* ldsA1 = As + 2048 + wave * 512;
    unsigned short* ldsB0 = Bs + wave * 512;
    unsigned short* ldsB1 = Bs + 2048 + wave * 512;

    for (int k0 = 0; k0 < K; k0 += 64) {
        async_copy16(gA0,      ldsA0);
        async_copy16(gA0 + 32, ldsA0 + 4096);
        async_copy16(gA1,      ldsA1);
        async_copy16(gA1 + 32, ldsA1 + 4096);
        async_copy16(gB0,      ldsB0);
        async_copy16(gB0 + 32, ldsB0 + 4096);
        async_copy16(gB1,      ldsB1);
        async_copy16(gB1 + 32, ldsB1 + 4096);
        gA0 += 64; gA1 += 64; gB0 += 64; gB1 += 64;
        __syncthreads();

#pragma unroll
        for (int s = 0; s < 2; s++) {
            frag_ab af[4], bfr[4];
#pragma unroll
            for (int i = 0; i < 4; i++)
                af[i] = *(const frag_ab*)&As[s * 4096 + (wm + i * 16 + lrow) * 32 + quad * 8];
#pragma unroll
            for (int j = 0; j < 4; j++)
                bfr[j] = *(const frag_ab*)&Bs[s * 4096 + (wn + j * 16 + lrow) * 32 + quad * 8];
#pragma unroll
            for (int i = 0; i < 4; i++)
#pragma unroll
                for (int j = 0; j < 4; j++)
                    acc[i][j] = __builtin_amdgcn_mfma_f32_16x16x32_bf16(
                        af[i], bfr[j], acc[i][j], 0, 0, 0);
        }
        __syncthreads();
    }

    // h1[row][col] = bf16(relu(acc + bias[col]))
#pragma unroll
    for (int j = 0; j < 4; j++) {
        const int col = bn + wn + j * 16 + lrow;
        const float bc = bias[col];
#pragma unroll
        for (int i = 0; i < 4; i++) {
            const int row0 = bm + wm + i * 16 + quad * 4;
#pragma unroll
            for (int r = 0; r < 4; r++) {
                float v = acc[i][j][r] + bc;
                v = v > 0.0f ? v : 0.0f;
                H[(size_t)(row0 + r) * EMBED + col] = f2bf(v);
            }
        }
    }
}

// ---------------------------------------------------------------------------
// Layer 2+3 (Q+V): out[row] += sum_n relu(h1 @ W2^T + b2)[n] * w3[n]
// ---------------------------------------------------------------------------
__global__ __launch_bounds__(256)
void layer2(const unsigned short* __restrict__ h1Q,
            const unsigned short* __restrict__ h1V,
            const unsigned short* __restrict__ Qw2t,
            const unsigned short* __restrict__ Vw2t,
            const float* __restrict__ Qb2, const float* __restrict__ Vb2,
            const float* __restrict__ Qw3, const float* __restrict__ Vw3,
            float* __restrict__ out) {
    __shared__ __align__(16) unsigned short As[2 * 4096];
    __shared__ __align__(16) unsigned short Bs[2 * 4096];

    const int tid = threadIdx.x, wave = tid >> 6, lane = tid & 63;
    int mi, nq; decode_mn(blockIdx.x, mi, nq);
    const bool isV = nq >= 4;
    const int bn = (nq & 3) * 128;
    const int bm = mi * 128;
    const unsigned short* A  = isV ? h1V : h1Q;
    const unsigned short* Wt = isV ? Vw2t : Qw2t;
    const float* bias = isV ? Vb2 : Qb2;
    const float* w3   = isV ? Vw3 : Qw3;
    float* op = out + (isV ? ROWS : 0);

    const int wm = (wave & 1) * 64, wn = (wave >> 1) * 64;
    const int lrow = lane & 15, quad = lane >> 4;
    f32x4 acc[4][4] = {};

    const int lin  = wave * 1024 + lane * 16;
    const int rowS = lin >> 6, colS = (lin & 63) >> 1;
    const unsigned short* gA0 = A  + (size_t)(bm + rowS)      * 512 + colS;
    const unsigned short* gA1 = A  + (size_t)(bm + rowS + 64) * 512 + colS;
    const unsigned short* gB0 = Wt + (size_t)(bn + rowS)      * 512 + colS;
    const unsigned short* gB1 = Wt + (size_t)(bn + rowS + 64) * 512 + colS;
    unsigned short* ldsA0 = As + wave * 512;
    unsigned short* ldsA1 = As + 2048 + wave * 512;
    unsigned short* ldsB0 = Bs + wave * 512;
    unsigned short* ldsB1 = Bs + 2048 + wave * 512;

    for (int k0 = 0; k0 < 512; k0 += 64) {
        async_copy16(gA0,      ldsA0);
        async_copy16(gA0 + 32, ldsA0 + 4096);
        async_copy16(gA1,      ldsA1);
        async_copy16(gA1 + 32, ldsA1 + 4096);
        async_copy16(gB0,      ldsB0);
        async_copy16(gB0 + 32, ldsB0 + 4096);
        async_copy16(gB1,      ldsB1);
        async_copy16(gB1 + 32, ldsB1 + 4096);
        gA0 += 64; gA1 += 64; gB0 += 64; gB1 += 64;
        __syncthreads();

#pragma unroll
        for (int s = 0; s < 2; s++) {
            frag_ab af[4], bfr[4];
#pragma unroll
            for (int i = 0; i < 4; i++)
                af[i] = *(const frag_ab*)&As[s * 4096 + (wm + i * 16 + lrow) * 32 + quad * 8];
#pragma unroll
            for (int j = 0; j < 4; j++)
                bfr[j] = *(const frag_ab*)&Bs[s * 4096 + (wn + j * 16 + lrow) * 32 + quad * 8];
#pragma unroll
            for (int i = 0; i < 4; i++)
#pragma unroll
                for (int j = 0; j < 4; j++)
                    acc[i][j] = __builtin_amdgcn_mfma_f32_16x16x32_bf16(
                        af[i], bfr[j], acc[i][j], 0, 0, 0);
        }
        __syncthreads();
    }

    float bc[4], wc[4];
#pragma unroll
    for (int j = 0; j < 4; j++) {
        const int col = bn + wn + j * 16 + lrow;
        bc[j] = bias[col];
        wc[j] = w3[col];
    }
#pragma unroll
    for (int i = 0; i < 4; i++) {
#pragma unroll
        for (int r = 0; r < 4; r++) {
            float s = 0.0f;
#pragma unroll
            for (int j = 0; j < 4; j++) {
                float v = acc[i][j][r] + bc[j];
                v = v > 0.0f ? v : 0.0f;
                s += v * wc[j];
            }
#pragma unroll
            for (int m = 1; m < 16; m <<= 1) s += __shfl_xor(s, m, 64);
            if (lrow == 0)
                atomicAdd(&op[bm + wm + i * 16 + quad * 4 + r], s);
        }
    }
}

extern "C" void kernel_launch(void* const* d_in, const int* in_sizes, int n_in,
                              void* d_out, int out_size, void* d_ws, size_t ws_size,
                              hipStream_t stream) {
    const float* states  = (const float*)d_in[0];
    const float* actions = (const float*)d_in[1];
    const float* Qw1 = (const float*)d_in[2];
    const float* Qb1 = (const float*)d_in[3];
    const float* Qw2 = (const float*)d_in[4];
    const float* Qb2 = (const float*)d_in[5];
    const float* Qw3 = (const float*)d_in[6];
    const float* Qb3 = (const float*)d_in[7];
    const float* Vw1 = (const float*)d_in[8];
    const float* Vb1 = (const float*)d_in[9];
    const float* Vw2 = (const float*)d_in[10];
    const float* Vb2 = (const float*)d_in[11];
    const float* Vw3 = (const float*)d_in[12];
    const float* Vb3 = (const float*)d_in[13];
    float* out = (float*)d_out;

    // workspace layout (bytes)
    char* ws = (char*)d_ws;
    unsigned short* X    = (unsigned short*)ws;                        // 64 MB
    unsigned short* h1Q  = (unsigned short*)(ws + 67108864);           // 32 MB
    unsigned short* h1V  = (unsigned short*)(ws + 100663296);          // 32 MB
    unsigned short* Qw1t = (unsigned short*)(ws + 134217728);          // 1 MB
    unsigned short* Qw2t = Qw1t + 512 * 1024;
    unsigned short* Vw1t = Qw2t + 512 * 512;
    unsigned short* Vw2t = Vw1t + 512 * 512;

    prep<<<dim3(4992), dim3(256), 0, stream>>>(states, actions, Qw1, Qw2, Vw1, Vw2,
                                               Qb3, Vb3, X, Qw1t, Qw2t, Vw1t, Vw2t, out);

    layer1<<<dim3(2048), dim3(256), 0, stream>>>(X, Qw1t, Vw1t, Qb1, Vb1, h1Q, h1V);
    layer2<<<dim3(2048), dim3(256), 0, stream>>>(h1Q, h1V, Qw2t, Vw2t, Qb2, Vb2, Qw3, Vw3, out);
}

// Round 6
// 287.599 us; speedup vs baseline: 1.2238x; 1.0582x over previous
//
#include <hip/hip_runtime.h>

// ---------------------------------------------------------------------------
// QTranBase: twin 3-layer MLPs via bf16 MFMA.
// R6: LDS-BW attack. R5 counters showed ~96 KB LDS moved per 128^2
// block-iter (~1000 cyc/CU) = saturated LDS pipe. Block tile 128x256,
// wave tile 64x128 (acc[4][8]): 146 KB per iter for 2x FLOPs = -24%
// LDS bytes/FLOP. Swizzle keeps the 4 same-m blocks on one XCD.
// ---------------------------------------------------------------------------

#define ROWS 32768
#define EMBED 512

using frag_ab = __attribute__((ext_vector_type(8))) short;   // 8 x bf16
using f32x4   = __attribute__((ext_vector_type(4))) float;   // MFMA C/D

__device__ __forceinline__ unsigned short f2bf(float f) {
    unsigned int u = __builtin_bit_cast(unsigned int, f);
    return (unsigned short)((u + 0x7fffu + ((u >> 16) & 1u)) >> 16);
}

__device__ __forceinline__ unsigned pk2rne(float lo, float hi) {
    return (unsigned)f2bf(lo) | ((unsigned)f2bf(hi) << 16);
}

__device__ __forceinline__ void async_copy16(const void* g, void* l) {
    // dest = wave-uniform LDS base; HW writes base + lane*16
    __builtin_amdgcn_global_load_lds(
        (const __attribute__((address_space(1))) unsigned int*)g,
        (__attribute__((address_space(3))) unsigned int*)l, 16, 0, 0);
}

// 1024 blocks -> (m-tile 0..255, nq 0..3); same-m (4 blocks) -> same XCD,
// adjacent dispatch window. nq: 0,1 = Q n-halves; 2,3 = V n-halves.
__device__ __forceinline__ void decode_mn(int L, int& mi, int& nq) {
    nq = (L >> 3) & 3;
    mi = ((L >> 5) << 3) | (L & 7);
}

// ---------------------------------------------------------------------------
// Fused prep: blocks [0,4096) convert X; [4096,4736) transpose weights;
// [4736,4992) seed out with layer-3 bias.
// ---------------------------------------------------------------------------
__global__ __launch_bounds__(256)
void prep(const float* __restrict__ states, const float* __restrict__ actions,
          const float* __restrict__ Qw1, const float* __restrict__ Qw2,
          const float* __restrict__ Vw1, const float* __restrict__ Vw2,
          const float* __restrict__ qb3, const float* __restrict__ vb3,
          unsigned short* __restrict__ X,
          unsigned short* __restrict__ Qw1t, unsigned short* __restrict__ Qw2t,
          unsigned short* __restrict__ Vw1t, unsigned short* __restrict__ Vw2t,
          float* __restrict__ out) {
    const int b = blockIdx.x, tid = threadIdx.x;
    if (b < 4096) {
        int c = b * 256 + tid;            // chunk of 32 within one row
        int m = c >> 5, col = (c & 31) * 32;
        const float* src = (col < 512) ? states + (size_t)m * 512 + col
                                       : actions + (size_t)m * 512 + (col - 512);
        float4 f[8];
#pragma unroll
        for (int i = 0; i < 8; i++) f[i] = ((const float4*)src)[i];
        uint4* dst = (uint4*)(X + (size_t)m * 1024 + col);
#pragma unroll
        for (int i = 0; i < 4; i++)
            dst[i] = make_uint4(pk2rne(f[2*i].x,   f[2*i].y),
                                pk2rne(f[2*i].z,   f[2*i].w),
                                pk2rne(f[2*i+1].x, f[2*i+1].y),
                                pk2rne(f[2*i+1].z, f[2*i+1].w));
    } else if (b < 4736) {
        int g = (b - 4096) * 256 + tid;
        const float* W; unsigned short* O; int n, k0, ldo;
        if (g < 65536) {                  // Qw1: [1024][512] -> [512][1024]
            int o = g * 8; n = o >> 10; k0 = o & 1023; W = Qw1; O = Qw1t; ldo = 1024;
        } else {
            g -= 65536;
            int seg = g >> 15, r = g & 32767, o = r * 8;
            n = o >> 9; k0 = o & 511; ldo = 512;
            W = (seg == 0) ? Qw2 : (seg == 1) ? Vw1 : Vw2;
            O = (seg == 0) ? Qw2t : (seg == 1) ? Vw1t : Vw2t;
        }
        float v[8];
#pragma unroll
        for (int j = 0; j < 8; j++) v[j] = W[(size_t)(k0 + j) * 512 + n];
        *(uint4*)(O + (size_t)n * ldo + k0) =
            make_uint4(pk2rne(v[0], v[1]), pk2rne(v[2], v[3]),
                       pk2rne(v[4], v[5]), pk2rne(v[6], v[7]));
    } else {
        int i = (b - 4736) * 256 + tid;
        out[i] = (i < ROWS) ? qb3[0] : vb3[0];
    }
}

// ---------------------------------------------------------------------------
// Layer 1 (Q+V): h1 = relu(X @ Wt^T + bias). nq<2 -> Q (K=1024),
// >=2 -> V (K=512). Block 128x256, waves 2x2 of 64x128, BK=64 (2 k-halves).
// ---------------------------------------------------------------------------
__global__ __launch_bounds__(256, 2)
void layer1(const unsigned short* __restrict__ X,
            const unsigned short* __restrict__ Qw1t,
            const unsigned short* __restrict__ Vw1t,
            const float* __restrict__ Qb1, const float* __restrict__ Vb1,
            unsigned short* __restrict__ h1Q, unsigned short* __restrict__ h1V) {
    __shared__ __align__(16) unsigned short As[2 * 4096];   // 16 KB: 2 halves x 128r x 32
    __shared__ __align__(16) unsigned short Bs[2 * 8192];   // 32 KB: 2 halves x 256r x 32

    const int tid = threadIdx.x, wave = tid >> 6, lane = tid & 63;
    int mi, nq; decode_mn(blockIdx.x, mi, nq);
    const bool isV = nq >= 2;
    const int bn = (nq & 1) * 256;
    const int bm = mi * 128;
    const int K = isV ? 512 : 1024;           // ldb == K for both weights
    const unsigned short* Wt = isV ? Vw1t : Qw1t;
    const float* bias = isV ? Vb1 : Qb1;
    unsigned short* H = isV ? h1V : h1Q;

    const int wm = (wave & 1) * 64, wn = (wave >> 1) * 128;
    const int lrow = lane & 15, quad = lane >> 4;
    f32x4 acc[4][8] = {};

    // staging geometry: per wave-instr, 64 lanes x 16 B = 16 rows of 64 B;
    // 4 waves together cover 64 rows per issue slot.
    const int lin  = wave * 1024 + lane * 16;
    const int rowS = lin >> 6, colS = (lin & 63) >> 1;
    const unsigned short* gA0 = X + (size_t)(bm + rowS)      * 1024 + colS;
    const unsigned short* gA1 = X + (size_t)(bm + rowS + 64) * 1024 + colS;
    const unsigned short* gB0 = Wt + (size_t)(bn + rowS)       * K + colS;
    const unsigned short* gB1 = Wt + (size_t)(bn + rowS + 64)  * K + colS;
    const unsigned short* gB2 = Wt + (size_t)(bn + rowS + 128) * K + colS;
    const unsigned short* gB3 = Wt + (size_t)(bn + rowS + 192) * K + colS;
    unsigned short* ldsA0 = As + wave * 512;           // rows 0-63, half 0
    unsigned short* ldsA1 = As + 2048 + wave * 512;    // rows 64-127
    unsigned short* ldsB0 = Bs + wave * 512;
    unsigned short* ldsB1 = Bs + 2048 + wave * 512;
    unsigned short* ldsB2 = Bs + 4096 + wave * 512;
    unsigned short* ldsB3 = Bs + 6144 + wave * 512;

    for (int k0 = 0; k0 < K; k0 += 64) {
        async_copy16(gA0,      ldsA0);
        async_copy16(gA0 + 32, ldsA0 + 4096);
        async_copy16(gA1,      ldsA1);
        async_copy16(gA1 + 32, ldsA1 + 4096);
        async_copy16(gB0,      ldsB0);
        async_copy16(gB0 + 32, ldsB0 + 8192);
        async_copy16(gB1,      ldsB1);
        async_copy16(gB1 + 32, ldsB1 + 8192);
        async_copy16(gB2,      ldsB2);
        async_copy16(gB2 + 32, ldsB2 + 8192);
        async_copy16(gB3,      ldsB3);
        async_copy16(gB3 + 32, ldsB3 + 8192);
        gA0 += 64; gA1 += 64; gB0 += 64; gB1 += 64; gB2 += 64; gB3 += 64;
        __syncthreads();

#pragma unroll
        for (int s = 0; s < 2; s++) {
            frag_ab af[4], bfr[8];
#pragma unroll
            for (int i = 0; i < 4; i++)
                af[i] = *(const frag_ab*)&As[s * 4096 + (wm + i * 16 + lrow) * 32 + quad * 8];
#pragma unroll
            for (int j = 0; j < 8; j++)
                bfr[j] = *(const frag_ab*)&Bs[s * 8192 + (wn + j * 16 + lrow) * 32 + quad * 8];
#pragma unroll
            for (int i = 0; i < 4; i++)
#pragma unroll
                for (int j = 0; j < 8; j++)
                    acc[i][j] = __builtin_amdgcn_mfma_f32_16x16x32_bf16(
                        af[i], bfr[j], acc[i][j], 0, 0, 0);
        }
        __syncthreads();
    }

    // h1[row][col] = bf16(relu(acc + bias[col]))
#pragma unroll
    for (int j = 0; j < 8; j++) {
        const int col = bn + wn + j * 16 + lrow;
        const float bc = bias[col];
#pragma unroll
        for (int i = 0; i < 4; i++) {
            const int row0 = bm + wm + i * 16 + quad * 4;
#pragma unroll
            for (int r = 0; r < 4; r++) {
                float v = acc[i][j][r] + bc;
                v = v > 0.0f ? v : 0.0f;
                H[(size_t)(row0 + r) * EMBED + col] = f2bf(v);
            }
        }
    }
}

// ---------------------------------------------------------------------------
// Layer 2+3 (Q+V): out[row] += sum_n relu(h1 @ W2^T + b2)[n] * w3[n]
// Same 128x256 tiling, K=512, fused layer-3 epilogue.
// ---------------------------------------------------------------------------
__global__ __launch_bounds__(256, 2)
void layer2(const unsigned short* __restrict__ h1Q,
            const unsigned short* __restrict__ h1V,
            const unsigned short* __restrict__ Qw2t,
            const unsigned short* __restrict__ Vw2t,
            const float* __restrict__ Qb2, const float* __restrict__ Vb2,
            const float* __restrict__ Qw3, const float* __restrict__ Vw3,
            float* __restrict__ out) {
    __shared__ __align__(16) unsigned short As[2 * 4096];
    __shared__ __align__(16) unsigned short Bs[2 * 8192];

    const int tid = threadIdx.x, wave = tid >> 6, lane = tid & 63;
    int mi, nq; decode_mn(blockIdx.x, mi, nq);
    const bool isV = nq >= 2;
    const int bn = (nq & 1) * 256;
    const int bm = mi * 128;
    const unsigned short* A  = isV ? h1V : h1Q;
    const unsigned short* Wt = isV ? Vw2t : Qw2t;
    const float* bias = isV ? Vb2 : Qb2;
    const float* w3   = isV ? Vw3 : Qw3;
    float* op = out + (isV ? ROWS : 0);

    const int wm = (wave & 1) * 64, wn = (wave >> 1) * 128;
    const int lrow = lane & 15, quad = lane >> 4;
    f32x4 acc[4][8] = {};

    const int lin  = wave * 1024 + lane * 16;
    const int rowS = lin >> 6, colS = (lin & 63) >> 1;
    const unsigned short* gA0 = A + (size_t)(bm + rowS)      * 512 + colS;
    const unsigned short* gA1 = A + (size_t)(bm + rowS + 64) * 512 + colS;
    const unsigned short* gB0 = Wt + (size_t)(bn + rowS)       * 512 + colS;
    const unsigned short* gB1 = Wt + (size_t)(bn + rowS + 64)  * 512 + colS;
    const unsigned short* gB2 = Wt + (size_t)(bn + rowS + 128) * 512 + colS;
    const unsigned short* gB3 = Wt + (size_t)(bn + rowS + 192) * 512 + colS;
    unsigned short* ldsA0 = As + wave * 512;
    unsigned short* ldsA1 = As + 2048 + wave * 512;
    unsigned short* ldsB0 = Bs + wave * 512;
    unsigned short* ldsB1 = Bs + 2048 + wave * 512;
    unsigned short* ldsB2 = Bs + 4096 + wave * 512;
    unsigned short* ldsB3 = Bs + 6144 + wave * 512;

    for (int k0 = 0; k0 < 512; k0 += 64) {
        async_copy16(gA0,      ldsA0);
        async_copy16(gA0 + 32, ldsA0 + 4096);
        async_copy16(gA1,      ldsA1);
        async_copy16(gA1 + 32, ldsA1 + 4096);
        async_copy16(gB0,      ldsB0);
        async_copy16(gB0 + 32, ldsB0 + 8192);
        async_copy16(gB1,      ldsB1);
        async_copy16(gB1 + 32, ldsB1 + 8192);
        async_copy16(gB2,      ldsB2);
        async_copy16(gB2 + 32, ldsB2 + 8192);
        async_copy16(gB3,      ldsB3);
        async_copy16(gB3 + 32, ldsB3 + 8192);
        gA0 += 64; gA1 += 64; gB0 += 64; gB1 += 64; gB2 += 64; gB3 += 64;
        __syncthreads();

#pragma unroll
        for (int s = 0; s < 2; s++) {
            frag_ab af[4], bfr[8];
#pragma unroll
            for (int i = 0; i < 4; i++)
                af[i] = *(const frag_ab*)&As[s * 4096 + (wm + i * 16 + lrow) * 32 + quad * 8];
#pragma unroll
            for (int j = 0; j < 8; j++)
                bfr[j] = *(const frag_ab*)&Bs[s * 8192 + (wn + j * 16 + lrow) * 32 + quad * 8];
#pragma unroll
            for (int i = 0; i < 4; i++)
#pragma unroll
                for (int j = 0; j < 8; j++)
                    acc[i][j] = __builtin_amdgcn_mfma_f32_16x16x32_bf16(
                        af[i], bfr[j], acc[i][j], 0, 0, 0);
        }
        __syncthreads();
    }

    float bc[8], wc[8];
#pragma unroll
    for (int j = 0; j < 8; j++) {
        const int col = bn + wn + j * 16 + lrow;
        bc[j] = bias[col];
        wc[j] = w3[col];
    }
#pragma unroll
    for (int i = 0; i < 4; i++) {
#pragma unroll
        for (int r = 0; r < 4; r++) {
            float s = 0.0f;
#pragma unroll
            for (int j = 0; j < 8; j++) {
                float v = acc[i][j][r] + bc[j];
                v = v > 0.0f ? v : 0.0f;
                s += v * wc[j];
            }
#pragma unroll
            for (int m = 1; m < 16; m <<= 1) s += __shfl_xor(s, m, 64);
            if (lrow == 0)
                atomicAdd(&op[bm + wm + i * 16 + quad * 4 + r], s);
        }
    }
}

extern "C" void kernel_launch(void* const* d_in, const int* in_sizes, int n_in,
                              void* d_out, int out_size, void* d_ws, size_t ws_size,
                              hipStream_t stream) {
    const float* states  = (const float*)d_in[0];
    const float* actions = (const float*)d_in[1];
    const float* Qw1 = (const float*)d_in[2];
    const float* Qb1 = (const float*)d_in[3];
    const float* Qw2 = (const float*)d_in[4];
    const float* Qb2 = (const float*)d_in[5];
    const float* Qw3 = (const float*)d_in[6];
    const float* Qb3 = (const float*)d_in[7];
    const float* Vw1 = (const float*)d_in[8];
    const float* Vb1 = (const float*)d_in[9];
    const float* Vw2 = (const float*)d_in[10];
    const float* Vb2 = (const float*)d_in[11];
    const float* Vw3 = (const float*)d_in[12];
    const float* Vb3 = (const float*)d_in[13];
    float* out = (float*)d_out;

    // workspace layout (bytes)
    char* ws = (char*)d_ws;
    unsigned short* X    = (unsigned short*)ws;                        // 64 MB
    unsigned short* h1Q  = (unsigned short*)(ws + 67108864);           // 32 MB
    unsigned short* h1V  = (unsigned short*)(ws + 100663296);          // 32 MB
    unsigned short* Qw1t = (unsigned short*)(ws + 134217728);          // 1 MB
    unsigned short* Qw2t = Qw1t + 512 * 1024;
    unsigned short* Vw1t = Qw2t + 512 * 512;
    unsigned short* Vw2t = Vw1t + 512 * 512;

    prep<<<dim3(4992), dim3(256), 0, stream>>>(states, actions, Qw1, Qw2, Vw1, Vw2,
                                               Qb3, Vb3, X, Qw1t, Qw2t, Vw1t, Vw2t, out);

    layer1<<<dim3(1024), dim3(256), 0, stream>>>(X, Qw1t, Vw1t, Qb1, Vb1, h1Q, h1V);
    layer2<<<dim3(1024), dim3(256), 0, stream>>>(h1Q, h1V, Qw2t, Vw2t, Qb2, Vb2, Qw3, Vw3, out);
}